// Round 1
// baseline (19.405 us; speedup 1.0000x reference)
//
#include <hip/hip_runtime.h>
#include <math.h>

// One block per batch row. Reduce T group elements with the non-commutative
// table op: op(later, earlier) = mul[later][earlier]. Then s_final = P * ID.
// logits[row][j] = (j == s_final) ? 0 : neg_fill.

#define BLK 256

__global__ __launch_bounds__(BLK) void a5_scan_kernel(
    const int* __restrict__ ids, const int* __restrict__ mul,
    const float* __restrict__ neg_fill, float* __restrict__ out,
    int T, int N)
{
    __shared__ int mul_lds[64 * 64];   // N<=64 supported; N=60 actual
    __shared__ int sp[BLK];
    __shared__ int s_final_sh;

    const int tid = threadIdx.x;
    const int row = blockIdx.x;
    const int NN = N * N;

    // Stage the multiplication table into LDS (cached in L1/L2 across blocks).
    for (int i = tid; i < NN; i += BLK) mul_lds[i] = mul[i];
    __syncthreads();

    const int* rowp = ids + (size_t)row * (size_t)T;
    const int chunk = T / BLK;              // 4096/256 = 16 (assumed divisible)
    const int base = tid * chunk;

    int p;  // product over this thread's contiguous segment, later-first
    if (chunk == 16) {
        // Fast path: vectorized loads, fully unrolled composition.
        int g[16];
        const int4* v = reinterpret_cast<const int4*>(rowp + base);
        #pragma unroll
        for (int k = 0; k < 4; ++k) {
            int4 x = v[k];
            g[4 * k + 0] = x.x; g[4 * k + 1] = x.y;
            g[4 * k + 2] = x.z; g[4 * k + 3] = x.w;
        }
        p = g[0];
        #pragma unroll
        for (int k = 1; k < 16; ++k) p = mul_lds[g[k] * N + p];
    } else {
        // Generic path: any chunk size, bounds-guarded. Empty segment -> id.
        p = -1;
        for (int k = base; k < base + chunk && k < T; ++k) {
            int gk = rowp[k];
            p = (p < 0) ? gk : mul_lds[gk * N + p];
        }
        if (p < 0) p = 0;  // ID_ID: identity element
    }

    sp[tid] = p;

    // Order-preserving adjacent-pair tree reduction:
    // new_P[i] = mul[P[2i+1]][P[2i]]  (later segment on the left).
    int cnt = BLK;
    while (cnt > 1) {
        __syncthreads();
        int t = 0;
        const int half = cnt >> 1;
        if (tid < half) {
            int a = sp[2 * tid];        // earlier
            int b = sp[2 * tid + 1];    // later
            t = mul_lds[b * N + a];
        }
        __syncthreads();
        if (tid < half) sp[tid] = t;
        cnt = half;
    }
    __syncthreads();

    if (tid == 0) {
        // Apply composed map to s0 = ID_ID (= 0): s_final = mul[P][0].
        s_final_sh = mul_lds[sp[0] * N + 0];
    }
    __syncthreads();

    const int sfin = s_final_sh;
    if (tid < N) {
        // reference: neg_fill * (1 - onehot) -> 0 at s_final, neg_fill else.
        out[(size_t)row * N + tid] = (tid == sfin) ? 0.0f : neg_fill[0];
    }
}

extern "C" void kernel_launch(void* const* d_in, const int* in_sizes, int n_in,
                              void* d_out, int out_size, void* d_ws, size_t ws_size,
                              hipStream_t stream) {
    const int* ids = (const int*)d_in[0];
    const int* mul = (const int*)d_in[1];
    const float* neg = (const float*)d_in[2];
    float* out = (float*)d_out;

    const int NN = in_sizes[1];
    int N = (int)(sqrt((double)NN) + 0.5);      // 60
    if (N * N != NN) N = 60;                    // safety
    const int B = out_size / N;                 // 4096
    const int T = in_sizes[0] / B;              // 4096

    a5_scan_kernel<<<dim3(B), dim3(BLK), 0, stream>>>(ids, mul, neg, out, T, N);
}